// Round 8
// baseline (697.241 us; speedup 1.0000x reference)
//
#include <hip/hip_runtime.h>
#include <hip/hip_bf16.h>

namespace {

constexpr int Bb = 512;
constexpr int Tt = 512;
constexpr int OD = 32;
constexpr int AD = 8;
constexpr int WL = 10;
constexpr int Nn = Tt - WL + 1;   // 503
constexpr int CH = OD + AD;       // 40
constexpr int REC_T = 512;        // padded steps (128 chunks x 4)

constexpr float LOG2E = 1.4426950408889634f;

constexpr long SZ_PO = (long)Bb * Nn * 32;
constexpr long SZ_PR = (long)Bb * Nn * 2;
constexpr long OFF_POST   = 0;
constexpr long OFF_PRIORS = SZ_PO;
constexpr long OFF_POSTS  = OFF_PRIORS + SZ_PR;
constexpr long OFF_XTRAJ  = OFF_POSTS + SZ_PR;
constexpr long OFF_TGT    = OFF_XTRAJ + SZ_PR;
constexpr long OFF_LAB    = OFF_TGT + SZ_PO;

constexpr int PK_W1  = 0;
constexpr int PK_W2  = 26624;
constexpr int PK_W3  = 30720;
constexpr int PK_DW1 = 31744;
constexpr int PK_DW2 = 33792;
constexpr int PK_DW3 = 37888;
constexpr int PK_TOTAL = 39936;

typedef __attribute__((ext_vector_type(8))) short bf16x8;
typedef __attribute__((ext_vector_type(4))) float f32x4;

__device__ __align__(16) short g_pack[PK_TOTAL];

__device__ __forceinline__ f32x4 mfma16(bf16x8 a, bf16x8 b, f32x4 c) {
  return __builtin_amdgcn_mfma_f32_16x16x32_bf16(a, b, c, 0, 0, 0);
}

__device__ __forceinline__ unsigned short f2bf(float x) {
  unsigned int u = __float_as_uint(x);
  unsigned int r = u + 0x7fffu + ((u >> 16) & 1u);
  return (unsigned short)(r >> 16);
}

__device__ __forceinline__ float sigmoidf_(float x) {
  return 1.0f / (1.0f + __expf(-x));
}
__device__ __forceinline__ float tanh_(float x) {
  return 1.0f - 2.0f / (__expf(2.0f * x) + 1.0f);
}

template <int CTRL>
__device__ __forceinline__ float dpp_add(float x) {
  int y = __builtin_amdgcn_update_dpp(0, __float_as_int(x), CTRL, 0xf, 0xf, false);
  return x + __int_as_float(y);
}
template <int CTRL>
__device__ __forceinline__ float dpp_mov(float x) {
  return __int_as_float(
      __builtin_amdgcn_update_dpp(0, __float_as_int(x), CTRL, 0xf, 0xf, false));
}
__device__ __forceinline__ float row16_allsum(float x) {
  x = dpp_add<0xB1>(x);
  x = dpp_add<0x4E>(x);
  x = dpp_add<0x141>(x);
  x = dpp_add<0x140>(x);
  return x;
}

// ---------------- weight prepack ----------------
__global__ __launch_bounds__(256) void pack_kernel(
    const float* __restrict__ W1, const float* __restrict__ W2,
    const float* __restrict__ W3, const float* __restrict__ dW1,
    const float* __restrict__ dW2, const float* __restrict__ dW3) {
  const int idx = blockIdx.x * 256 + threadIdx.x;
  if (idx >= PK_TOTAL) return;
  float v = 0.0f;
  int base, r;
  if (idx < PK_W2) {
    base = PK_W1; r = idx - base;
    const int frag = r >> 9, inner = r & 511;
    const int lane = inner >> 3, j = inner & 7;
    const int kb = frag >> 2, jb = frag & 3;
    const int col = lane & 15;
    const int kp = kb * 32 + ((lane >> 4) << 3) + j;
    if (kp < 400) {
      const int w = kp / 40, c = kp - w * 40;
      v = W1[(c * 10 + w) * 64 + jb * 16 + col];
    }
  } else if (idx < PK_W3) {
    base = PK_W2; r = idx - base;
    const int frag = r >> 9, inner = r & 511;
    const int lane = inner >> 3, j = inner & 7;
    const int kb = frag >> 2, jb = frag & 3;
    const int col = lane & 15;
    const int k = kb * 32 + ((lane >> 4) << 3) + j;
    v = W2[k * 64 + jb * 16 + col];
  } else if (idx < PK_DW1) {
    base = PK_W3; r = idx - base;
    const int frag = r >> 9, inner = r & 511;
    const int lane = inner >> 3, j = inner & 7;
    const int kb = frag;
    const int col = lane & 15;
    const int k = kb * 32 + ((lane >> 4) << 3) + j;
    v = (col < 2) ? W3[k * 2 + col] : 0.0f;
  } else if (idx < PK_DW2) {
    base = PK_DW1; r = idx - base;
    const int frag = r >> 9, inner = r & 511;
    const int lane = inner >> 3, j = inner & 7;
    const int jb = frag;
    const int col = lane & 15;
    const int k = ((lane >> 4) << 3) + j;
    v = (k < 10) ? dW1[k * 64 + jb * 16 + col] : 0.0f;
  } else if (idx < PK_DW3) {
    base = PK_DW2; r = idx - base;
    const int frag = r >> 9, inner = r & 511;
    const int lane = inner >> 3, j = inner & 7;
    const int kb = frag >> 2, jb = frag & 3;
    const int col = lane & 15;
    const int k = kb * 32 + ((lane >> 4) << 3) + j;
    v = dW2[k * 64 + jb * 16 + col];
  } else {
    base = PK_DW3; r = idx - base;
    const int frag = r >> 9, inner = r & 511;
    const int lane = inner >> 3, j = inner & 7;
    const int kb = frag >> 1, jb = frag & 1;
    const int col = lane & 15;
    const int k = kb * 32 + ((lane >> 4) << 3) + j;
    v = dW3[k * 32 + jb * 16 + col];
  }
  g_pack[idx] = (short)f2bf(v);
}

// ---------------- copies ----------------
__global__ void copy_kernel(const float* __restrict__ obs,
                            const int* __restrict__ tlab,
                            float* __restrict__ out) {
  const int total4 = (int)(SZ_PO / 4);
  const int totalL = Bb * Nn;
  const int stride = gridDim.x * blockDim.x;
  float4* out4 = reinterpret_cast<float4*>(out + OFF_TGT);
  const float4* obs4 = reinterpret_cast<const float4*>(obs);
  for (int idx = blockIdx.x * blockDim.x + threadIdx.x;
       idx < total4 + totalL; idx += stride) {
    if (idx < total4) {
      const int b = idx / (Nn * 8);
      const int r = idx - b * (Nn * 8);
      const int n = r >> 3;
      const int c4 = r & 7;
      out4[idx] = obs4[((long)b * Tt + n + WL - 1) * 8 + c4];
    } else {
      const int j = idx - total4;
      const int b = j / Nn;
      const int n = j - b * Nn;
      out[OFF_LAB + j] = (float)tlab[(long)b * Tt + n + WL - 1];
    }
  }
}

// ---------------- encoder (MFMA) ----------------
__global__ __launch_bounds__(256) void enc_mfma(
    const float* __restrict__ obs, const float* __restrict__ act,
    const float* __restrict__ b1, const float* __restrict__ b2,
    const float* __restrict__ b3, float* __restrict__ out) {
  __shared__ __align__(16) unsigned short sA[74 * 40];
  __shared__ __align__(16) unsigned short sH1[64 * 64];
  __shared__ __align__(16) unsigned short sH2[64 * 64];
  const int b = blockIdx.x >> 3;
  const int n0 = (blockIdx.x & 7) << 6;
  const int tid = threadIdx.x;
  const int lane = tid & 63, wv = tid >> 6;
  const int q = lane >> 4, lr = lane & 15;
  const int nl = wv * 16 + lr;

  for (int e = tid; e < 74 * 40; e += 256) {
    const int row = e / 40, c = e - row * 40;
    int t = n0 + row; t = t < Tt ? t : Tt - 1;
    const float v = (c < OD) ? obs[((long)b * Tt + t) * OD + c]
                             : act[((long)b * Tt + t) * AD + c - OD];
    sA[e] = f2bf(v);
  }
  __syncthreads();

  const char* sAb = (const char*)sA;
  f32x4 acc[4] = {{0,0,0,0},{0,0,0,0},{0,0,0,0},{0,0,0,0}};
  {
    int c0 = q * 8, w = 0;
#pragma unroll
    for (int kb = 0; kb < 13; ++kb) {
      const bf16x8 a = *(const bf16x8*)(sAb + (nl + w) * 80 + c0 * 2);
#pragma unroll
      for (int jb = 0; jb < 4; ++jb) {
        const bf16x8 bw =
            *(const bf16x8*)&g_pack[PK_W1 + ((kb * 4 + jb) * 64 + lane) * 8];
        acc[jb] = mfma16(a, bw, acc[jb]);
      }
      c0 += 32;
      if (c0 >= 40) { c0 -= 40; ++w; }
    }
  }
  {
#pragma unroll
    for (int jb = 0; jb < 4; ++jb) {
      const float bb = b1[jb * 16 + lr];
#pragma unroll
      for (int r = 0; r < 4; ++r) {
        const int grow = wv * 16 + q * 4 + r;
        const int col = jb * 16 + lr;
        const float v = fmaxf(acc[jb][r] + bb, 0.0f);
        const int byte = (grow * 128 + col * 2) ^ ((grow & 7) << 4);
        *(unsigned short*)((char*)sH1 + byte) = f2bf(v);
      }
    }
  }
  __syncthreads();

  f32x4 ac2[4] = {{0,0,0,0},{0,0,0,0},{0,0,0,0},{0,0,0,0}};
#pragma unroll
  for (int kb = 0; kb < 2; ++kb) {
    const int byte = (nl * 128 + kb * 64 + q * 16) ^ ((lr & 7) << 4);
    const bf16x8 a = *(const bf16x8*)((const char*)sH1 + byte);
#pragma unroll
    for (int jb = 0; jb < 4; ++jb) {
      const bf16x8 bw =
          *(const bf16x8*)&g_pack[PK_W2 + ((kb * 4 + jb) * 64 + lane) * 8];
      ac2[jb] = mfma16(a, bw, ac2[jb]);
    }
  }
  {
#pragma unroll
    for (int jb = 0; jb < 4; ++jb) {
      const float bb = b2[jb * 16 + lr];
#pragma unroll
      for (int r = 0; r < 4; ++r) {
        const int grow = wv * 16 + q * 4 + r;
        const int col = jb * 16 + lr;
        const float v = fmaxf(ac2[jb][r] + bb, 0.0f);
        const int byte = (grow * 128 + col * 2) ^ ((grow & 7) << 4);
        *(unsigned short*)((char*)sH2 + byte) = f2bf(v);
      }
    }
  }
  __syncthreads();

  f32x4 ac3 = {0, 0, 0, 0};
#pragma unroll
  for (int kb = 0; kb < 2; ++kb) {
    const int byte = (nl * 128 + kb * 64 + q * 16) ^ ((lr & 7) << 4);
    const bf16x8 a = *(const bf16x8*)((const char*)sH2 + byte);
    const bf16x8 bw = *(const bf16x8*)&g_pack[PK_W3 + (kb * 64 + lane) * 8];
    ac3 = mfma16(a, bw, ac3);
  }
  if (lr < 2) {
    const float bb = b3[lr];
#pragma unroll
    for (int r = 0; r < 4; ++r) {
      const int grow = wv * 16 + q * 4 + r;
      const int n = n0 + grow;
      if (n < Nn) out[OFF_PRIORS + ((long)b * Nn + n) * 2 + lr] = ac3[r] + bb;
    }
  }
}

// ---------------- decoder (MFMA) ----------------
__global__ __launch_bounds__(256) void dec_mfma(
    const float* __restrict__ act, const float* __restrict__ b1,
    const float* __restrict__ b2, const float* __restrict__ b3,
    float* __restrict__ out) {
  __shared__ __align__(16) unsigned short sD[64 * 32];
  __shared__ __align__(16) unsigned short sH1[64 * 64];
  __shared__ __align__(16) unsigned short sH2[64 * 64];
  const int b = blockIdx.x >> 3;
  const int n0 = (blockIdx.x & 7) << 6;
  const int tid = threadIdx.x;
  const int lane = tid & 63, wv = tid >> 6;
  const int q = lane >> 4, lr = lane & 15;
  const int nl = wv * 16 + lr;
  const float* posts = out + OFF_POSTS;

  for (int e = tid; e < 64 * 32; e += 256) {
    const int row = e >> 5, c = e & 31;
    int n = n0 + row; n = n < Nn ? n : Nn - 1;
    float v = 0.0f;
    if (c < 2) v = posts[((long)b * Nn + n) * 2 + c];
    else if (c < 10) v = act[((long)b * Tt + n + WL - 1) * AD + c - 2];
    const int byte = (row * 64 + c * 2) ^ ((row & 3) << 4);
    *(unsigned short*)((char*)sD + byte) = f2bf(v);
  }
  __syncthreads();

  f32x4 acc[4] = {{0,0,0,0},{0,0,0,0},{0,0,0,0},{0,0,0,0}};
  {
    const int byte = (nl * 64 + q * 16) ^ ((nl & 3) << 4);
    const bf16x8 a = *(const bf16x8*)((const char*)sD + byte);
#pragma unroll
    for (int jb = 0; jb < 4; ++jb) {
      const bf16x8 bw = *(const bf16x8*)&g_pack[PK_DW1 + (jb * 64 + lane) * 8];
      acc[jb] = mfma16(a, bw, acc[jb]);
    }
  }
  {
#pragma unroll
    for (int jb = 0; jb < 4; ++jb) {
      const float bb = b1[jb * 16 + lr];
#pragma unroll
      for (int r = 0; r < 4; ++r) {
        const int grow = wv * 16 + q * 4 + r;
        const int col = jb * 16 + lr;
        const float v = fmaxf(acc[jb][r] + bb, 0.0f);
        const int byte = (grow * 128 + col * 2) ^ ((grow & 7) << 4);
        *(unsigned short*)((char*)sH1 + byte) = f2bf(v);
      }
    }
  }
  __syncthreads();

  f32x4 ac2[4] = {{0,0,0,0},{0,0,0,0},{0,0,0,0},{0,0,0,0}};
#pragma unroll
  for (int kb = 0; kb < 2; ++kb) {
    const int byte = (nl * 128 + kb * 64 + q * 16) ^ ((lr & 7) << 4);
    const bf16x8 a = *(const bf16x8*)((const char*)sH1 + byte);
#pragma unroll
    for (int jb = 0; jb < 4; ++jb) {
      const bf16x8 bw =
          *(const bf16x8*)&g_pack[PK_DW2 + ((kb * 4 + jb) * 64 + lane) * 8];
      ac2[jb] = mfma16(a, bw, ac2[jb]);
    }
  }
  {
#pragma unroll
    for (int jb = 0; jb < 4; ++jb) {
      const float bb = b2[jb * 16 + lr];
#pragma unroll
      for (int r = 0; r < 4; ++r) {
        const int grow = wv * 16 + q * 4 + r;
        const int col = jb * 16 + lr;
        const float v = fmaxf(ac2[jb][r] + bb, 0.0f);
        const int byte = (grow * 128 + col * 2) ^ ((grow & 7) << 4);
        *(unsigned short*)((char*)sH2 + byte) = f2bf(v);
      }
    }
  }
  __syncthreads();

  f32x4 ac3[2] = {{0,0,0,0},{0,0,0,0}};
#pragma unroll
  for (int kb = 0; kb < 2; ++kb) {
    const int byte = (nl * 128 + kb * 64 + q * 16) ^ ((lr & 7) << 4);
    const bf16x8 a = *(const bf16x8*)((const char*)sH2 + byte);
#pragma unroll
    for (int jb = 0; jb < 2; ++jb) {
      const bf16x8 bw =
          *(const bf16x8*)&g_pack[PK_DW3 + ((kb * 2 + jb) * 64 + lane) * 8];
      ac3[jb] = mfma16(a, bw, ac3[jb]);
    }
  }
#pragma unroll
  for (int jb = 0; jb < 2; ++jb) {
    const int o = jb * 16 + lr;
    const float bb = b3[o];
#pragma unroll
    for (int r = 0; r < 4; ++r) {
      const int grow = wv * 16 + q * 4 + r;
      const int n = n0 + grow;
      if (n < Nn) out[OFF_POST + ((long)b * Nn + n) * 32 + o] = ac3[jb][r] + bb;
    }
  }
}

// ---------------- gprep: records in [blk(32)][t][c16][12] layout ----------------
__global__ __launch_bounds__(256) void gprep_kernel(
    const float* __restrict__ act, const int* __restrict__ mask,
    const float* __restrict__ Wih, const float* __restrict__ bih,
    const float* __restrict__ out, float* __restrict__ rec) {
  const int idx = blockIdx.x * 256 + threadIdx.x;
  const int total = Bb * REC_T;
  if (idx >= total) return;
  const int c16 = idx & 15;
  const int t = (idx >> 4) & (REC_T - 1);
  const int blk = idx >> 13;
  const int g = (blk << 4) + c16;
  const float sc[6] = {-LOG2E, -LOG2E, -LOG2E, -LOG2E, 2.f * LOG2E, 2.f * LOG2E};
  float r[12];
#pragma unroll
  for (int i = 0; i < 12; ++i) r[i] = 0.0f;
  if (t < Nn - 1) {
    const float* a = act + ((long)g * Tt + WL - 1 + t) * AD;
    const float4 a0 = *reinterpret_cast<const float4*>(a);
    const float4 a1 = *reinterpret_cast<const float4*>(a + 4);
#pragma unroll
    for (int q = 0; q < 6; ++q) {
      float acc = bih[q];
      acc = fmaf(a0.x, Wih[0 * 6 + q], acc);
      acc = fmaf(a0.y, Wih[1 * 6 + q], acc);
      acc = fmaf(a0.z, Wih[2 * 6 + q], acc);
      acc = fmaf(a0.w, Wih[3 * 6 + q], acc);
      acc = fmaf(a1.x, Wih[4 * 6 + q], acc);
      acc = fmaf(a1.y, Wih[5 * 6 + q], acc);
      acc = fmaf(a1.z, Wih[6 * 6 + q], acc);
      acc = fmaf(a1.w, Wih[7 * 6 + q], acc);
      r[q] = acc * sc[q];
    }
    const float2 pr =
        *reinterpret_cast<const float2*>(out + OFF_PRIORS + ((long)g * Nn + t) * 2);
    r[6] = pr.x;
    r[7] = pr.y;
    r[8] = (float)mask[(long)g * Nn + t];
  }
  float4* o = reinterpret_cast<float4*>(rec + (long)idx * 12);
  o[0] = make_float4(r[0], r[1], r[2], r[3]);
  o[1] = make_float4(r[4], r[5], r[6], r[7]);
  o[2] = make_float4(r[8], r[9], r[10], r[11]);
}

// ---------------- scan v7: 4-way chain interleave + LDS dbuf + exp2/rcp ----------------
#define SCAN_STEP(GA, GB, MF, TG, X0, X1, S0, S1, XW, SW, LX, LS)           \
  do {                                                                      \
    const bool mm = ((MF) != 0.0f);                                         \
    const float st0 = mm ? (GB).z : S0;                                     \
    const float st1 = mm ? (GB).w : S1;                                     \
    float giq[6], ghq[6];                                                   \
    _Pragma("unroll") for (int q_ = 0; q_ < 6; ++q_) ghq[q_] =              \
        fmaf(X1, whh1[q_], fmaf(X0, whh0[q_], bhhv[q_]));                   \
    giq[0] = fmaf(st1, wih9[0], fmaf(st0, wih8[0], (GA).x));                \
    giq[1] = fmaf(st1, wih9[1], fmaf(st0, wih8[1], (GA).y));                \
    giq[2] = fmaf(st1, wih9[2], fmaf(st0, wih8[2], (GA).z));                \
    giq[3] = fmaf(st1, wih9[3], fmaf(st0, wih8[3], (GA).w));                \
    giq[4] = fmaf(st1, wih9[4], fmaf(st0, wih8[4], (GB).x));                \
    giq[5] = fmaf(st1, wih9[5], fmaf(st0, wih8[5], (GB).y));                \
    const float e0 = __builtin_amdgcn_exp2f(giq[0] + ghq[0]);               \
    const float e1 = __builtin_amdgcn_exp2f(giq[1] + ghq[1]);               \
    const float e2 = __builtin_amdgcn_exp2f(giq[2] + ghq[2]);               \
    const float e3 = __builtin_amdgcn_exp2f(giq[3] + ghq[3]);               \
    const float r0 = __builtin_amdgcn_rcpf(1.0f + e0);                      \
    const float r1 = __builtin_amdgcn_rcpf(1.0f + e1);                      \
    const float z0 = __builtin_amdgcn_rcpf(1.0f + e2);                      \
    const float z1 = __builtin_amdgcn_rcpf(1.0f + e3);                      \
    const float en0 = __builtin_amdgcn_exp2f(fmaf(r0, ghq[4], giq[4]));     \
    const float en1 = __builtin_amdgcn_exp2f(fmaf(r1, ghq[5], giq[5]));     \
    const float nn0 = fmaf(-2.0f, __builtin_amdgcn_rcpf(1.0f + en0), 1.0f); \
    const float nn1 = fmaf(-2.0f, __builtin_amdgcn_rcpf(1.0f + en1), 1.0f); \
    const float xn0 = fmaf(z0, X0 - nn0, nn0);                              \
    const float xn1 = fmaf(z1, X1 - nn1, nn1);                              \
    const float h1 = fmaxf(fmaf(xn1, w1c1, fmaf(xn0, w1c0, b1v)), 0.0f);    \
    const float t0 = h1;                                                    \
    const float t1 = dpp_mov<0xB1>(t0);                                     \
    const float t2 = dpp_mov<0x4E>(t0);                                     \
    const float t3 = dpp_mov<0x4E>(t1);                                     \
    const float t4 = dpp_mov<0x141>(t0);                                    \
    const float t5 = dpp_mov<0x141>(t1);                                    \
    const float t6 = dpp_mov<0x141>(t2);                                    \
    const float t7 = dpp_mov<0x141>(t3);                                    \
    const float t8 = dpp_mov<0x128>(t0);                                    \
    const float t9 = dpp_mov<0x128>(t1);                                    \
    const float t10 = dpp_mov<0x128>(t2);                                   \
    const float t11 = dpp_mov<0x128>(t3);                                   \
    const float t12 = dpp_mov<0x128>(t4);                                   \
    const float t13 = dpp_mov<0x128>(t5);                                   \
    const float t14 = dpp_mov<0x128>(t6);                                   \
    const float t15 = dpp_mov<0x128>(t7);                                   \
    float q0 = fmaf(t0, wg[0], b2v);                                        \
    q0 = fmaf(t1, wg[1], q0);                                               \
    q0 = fmaf(t2, wg[2], q0);                                               \
    q0 = fmaf(t3, wg[3], q0);                                               \
    float q1 = t4 * wg[4];                                                  \
    q1 = fmaf(t5, wg[5], q1);                                               \
    q1 = fmaf(t6, wg[6], q1);                                               \
    q1 = fmaf(t7, wg[7], q1);                                               \
    float q2 = t8 * wg[8];                                                  \
    q2 = fmaf(t9, wg[9], q2);                                               \
    q2 = fmaf(t10, wg[10], q2);                                             \
    q2 = fmaf(t11, wg[11], q2);                                             \
    float q3 = t12 * wg[12];                                                \
    q3 = fmaf(t13, wg[13], q3);                                             \
    q3 = fmaf(t14, wg[14], q3);                                             \
    q3 = fmaf(t15, wg[15], q3);                                             \
    const float h2 = fmaxf((q0 + q1) + (q2 + q3), 0.0f);                    \
    float p0 = row16_allsum(h2 * w3a);                                      \
    float p1 = row16_allsum(h2 * w3b);                                      \
    const float sn0 = p0 + b3a;                                             \
    const float sn1 = p1 + b3b;                                             \
    if (lane == (LX) && (TG) < Nn - 1)                                      \
      *reinterpret_cast<float2*>(XW) = make_float2(xn0, xn1);               \
    if (lane == (LS) && (TG) < Nn - 1)                                      \
      *reinterpret_cast<float2*>(SW) = make_float2(sn0, sn1);               \
    XW += 2;                                                                \
    SW += 2;                                                                \
    X0 = xn0;                                                               \
    X1 = xn1;                                                               \
    S0 = sn0;                                                               \
    S1 = sn1;                                                               \
  } while (0)

#define LOADCH(C)                                                     \
  do {                                                                \
    const float* p_ = gsrc + (C) * 768 + tid * 12;                    \
    st0 = *reinterpret_cast<const float4*>(p_);                       \
    st1 = *reinterpret_cast<const float4*>(p_ + 4);                   \
    st2 = *reinterpret_cast<const float4*>(p_ + 8);                   \
  } while (0)
#define WRITECH(BUF)                                                  \
  do {                                                                \
    float* q_ = &slds[BUF][tid * 12];                                 \
    *reinterpret_cast<float4*>(q_) = st0;                             \
    *reinterpret_cast<float4*>(q_ + 4) = st1;                         \
    *reinterpret_cast<float4*>(q_ + 8) = st2;                         \
  } while (0)
#define PFSTEP(CGA, CGB, CMF, NB, NT, C16)                            \
  do {                                                                \
    const float* rp_ = &slds[NB][(((NT)*16) + (C16)) * 12];           \
    CGA = *reinterpret_cast<const float4*>(rp_);                      \
    CGB = *reinterpret_cast<const float4*>(rp_ + 4);                  \
    CMF = rp_[8];                                                     \
  } while (0)

__global__ __launch_bounds__(64, 1) void scan5_kernel(
    const float* __restrict__ rec, const float* __restrict__ pW2,
    const float* __restrict__ pW1, const float* __restrict__ pb1,
    const float* __restrict__ pb2, const float* __restrict__ pW3,
    const float* __restrict__ pb3, const float* __restrict__ Wih,
    const float* __restrict__ Whh, const float* __restrict__ bhh,
    float* __restrict__ out) {
  __shared__ __align__(16) float slds[2][768];
  const int tid = threadIdx.x;
  const int lane = tid & 15;
  const int sub = tid >> 4;          // 0..3
  const int blk = blockIdx.x;        // 0..31
  const int gA = (blk << 4) + sub;
  const int gB = gA + 4;
  const int gC = gA + 8;
  const int gD = gA + 12;

  const float sc[6] = {-LOG2E, -LOG2E, -LOG2E, -LOG2E, 2.f * LOG2E, 2.f * LOG2E};
  float wih8[6], wih9[6], whh0[6], whh1[6], bhhv[6];
#pragma unroll
  for (int q = 0; q < 6; ++q) {
    wih8[q] = Wih[8 * 6 + q] * sc[q];
    wih9[q] = Wih[9 * 6 + q] * sc[q];
    whh0[q] = Whh[q] * sc[q];
    whh1[q] = Whh[6 + q] * sc[q];
    bhhv[q] = bhh[q] * sc[q];
  }
  const float w1c0 = pW1[lane], w1c1 = pW1[16 + lane], b1v = pb1[lane];
  constexpr int otab[16] = {0, 1, 2, 3, 7, 6, 5, 4, 8, 9, 10, 11, 15, 14, 13, 12};
  float wg[16];
#pragma unroll
  for (int i = 0; i < 16; ++i) wg[i] = pW2[(lane ^ otab[i]) * 16 + lane];
  const float b2v = pb2[lane];
  const float w3a = pW3[lane * 2], w3b = pW3[lane * 2 + 1];
  const float b3a = pb3[0], b3b = pb3[1];

  const float* priors = out + OFF_PRIORS;
  const float* gsrc = rec + (long)blk * (REC_T * 192);  // 16 chains * 12

  float* xwA = out + OFF_XTRAJ + (long)gA * Nn * 2 + 2;
  float* swA = out + OFF_POSTS + (long)gA * Nn * 2 + 2;
  float* xwB = out + OFF_XTRAJ + (long)gB * Nn * 2 + 2;
  float* swB = out + OFF_POSTS + (long)gB * Nn * 2 + 2;
  float* xwC = out + OFF_XTRAJ + (long)gC * Nn * 2 + 2;
  float* swC = out + OFF_POSTS + (long)gC * Nn * 2 + 2;
  float* xwD = out + OFF_XTRAJ + (long)gD * Nn * 2 + 2;
  float* swD = out + OFF_POSTS + (long)gD * Nn * 2 + 2;

  // init state from priors[:,0,:]
  float x0A = 0.f, x1A = 0.f, s0A, s1A;
  float x0B = 0.f, x1B = 0.f, s0B, s1B;
  float x0C = 0.f, x1C = 0.f, s0C, s1C;
  float x0D = 0.f, x1D = 0.f, s0D, s1D;
  {
    const float2 a = *reinterpret_cast<const float2*>(priors + (long)gA * Nn * 2);
    const float2 b = *reinterpret_cast<const float2*>(priors + (long)gB * Nn * 2);
    const float2 c = *reinterpret_cast<const float2*>(priors + (long)gC * Nn * 2);
    const float2 d = *reinterpret_cast<const float2*>(priors + (long)gD * Nn * 2);
    s0A = a.x; s1A = a.y; s0B = b.x; s1B = b.y;
    s0C = c.x; s1C = c.y; s0D = d.x; s1D = d.y;
    if (lane == 0) {
      *reinterpret_cast<float2*>(out + OFF_XTRAJ + (long)gA * Nn * 2) = make_float2(0.f, 0.f);
      *reinterpret_cast<float2*>(out + OFF_POSTS + (long)gA * Nn * 2) = a;
    }
    if (lane == 1) {
      *reinterpret_cast<float2*>(out + OFF_XTRAJ + (long)gB * Nn * 2) = make_float2(0.f, 0.f);
      *reinterpret_cast<float2*>(out + OFF_POSTS + (long)gB * Nn * 2) = b;
    }
    if (lane == 2) {
      *reinterpret_cast<float2*>(out + OFF_XTRAJ + (long)gC * Nn * 2) = make_float2(0.f, 0.f);
      *reinterpret_cast<float2*>(out + OFF_POSTS + (long)gC * Nn * 2) = c;
    }
    if (lane == 3) {
      *reinterpret_cast<float2*>(out + OFF_XTRAJ + (long)gD * Nn * 2) = make_float2(0.f, 0.f);
      *reinterpret_cast<float2*>(out + OFF_POSTS + (long)gD * Nn * 2) = d;
    }
  }

  float4 st0, st1, st2;
  LOADCH(0);
  WRITECH(0);
  LOADCH(1);

  float4 cGAa, cGBa, cGAb, cGBb, cGAc, cGBc, cGAd, cGBd;
  float cMFa, cMFb, cMFc, cMFd;
  PFSTEP(cGAa, cGBa, cMFa, 0, 0, sub);
  PFSTEP(cGAb, cGBb, cMFb, 0, 0, sub + 4);
  PFSTEP(cGAc, cGBc, cMFc, 0, 0, sub + 8);
  PFSTEP(cGAd, cGBd, cMFd, 0, 0, sub + 12);

  int tg = 0;
  for (int c = 0; c < 128; ++c) {
    const int buf = c & 1;
    if (c + 1 < 128) WRITECH((c + 1) & 1);
    if (c + 2 < 128) LOADCH(c + 2);
#pragma unroll
    for (int tl = 0; tl < 4; ++tl) {
      const float4 GAa = cGAa, GBa = cGBa;
      const float4 GAb = cGAb, GBb = cGBb;
      const float4 GAc = cGAc, GBc = cGBc;
      const float4 GAd = cGAd, GBd = cGBd;
      const float MFa = cMFa, MFb = cMFb, MFc = cMFc, MFd = cMFd;
      const int ntl = (tl + 1) & 3;
      const int nbuf = (tl == 3) ? (buf ^ 1) : buf;
      PFSTEP(cGAa, cGBa, cMFa, nbuf, ntl, sub);
      PFSTEP(cGAb, cGBb, cMFb, nbuf, ntl, sub + 4);
      PFSTEP(cGAc, cGBc, cMFc, nbuf, ntl, sub + 8);
      PFSTEP(cGAd, cGBd, cMFd, nbuf, ntl, sub + 12);
      SCAN_STEP(GAa, GBa, MFa, tg, x0A, x1A, s0A, s1A, xwA, swA, 0, 1);
      SCAN_STEP(GAb, GBb, MFb, tg, x0B, x1B, s0B, s1B, xwB, swB, 2, 3);
      SCAN_STEP(GAc, GBc, MFc, tg, x0C, x1C, s0C, s1C, xwC, swC, 4, 5);
      SCAN_STEP(GAd, GBd, MFd, tg, x0D, x1D, s0D, s1D, xwD, swD, 6, 7);
      ++tg;
    }
  }
}

// ---------------- fallback scan (no workspace) ----------------
__global__ __launch_bounds__(64) void scan_fb_kernel(
    const float* __restrict__ act, const int* __restrict__ mask,
    const float* __restrict__ Wih, const float* __restrict__ Whh,
    const float* __restrict__ bih, const float* __restrict__ bhh,
    const float* __restrict__ pW1, const float* __restrict__ pb1,
    const float* __restrict__ pW2, const float* __restrict__ pb2,
    const float* __restrict__ pW3, const float* __restrict__ pb3,
    float* __restrict__ out) {
  const int tid = threadIdx.x;
  const int lane = tid & 15;
  const int g = (blockIdx.x * 64 + tid) >> 4;

  float wih8[6], wih9[6], whh0[6], whh1[6], bhhv[6], bihv[6];
  float wihA[8][6];
#pragma unroll
  for (int q = 0; q < 6; ++q) {
    wih8[q] = Wih[8 * 6 + q];
    wih9[q] = Wih[9 * 6 + q];
    whh0[q] = Whh[q];
    whh1[q] = Whh[6 + q];
    bhhv[q] = bhh[q];
    bihv[q] = bih[q];
  }
#pragma unroll
  for (int i = 0; i < 8; ++i)
#pragma unroll
    for (int q = 0; q < 6; ++q) wihA[i][q] = Wih[i * 6 + q];

  const float w1c0 = pW1[lane], w1c1 = pW1[16 + lane], b1v = pb1[lane];
  float w2c[16];
#pragma unroll
  for (int k = 0; k < 16; ++k) w2c[k] = pW2[k * 16 + lane];
  const float b2v = pb2[lane];
  const float w3a = pW3[lane * 2], w3b = pW3[lane * 2 + 1];
  const float b3a = pb3[0], b3b = pb3[1];

  const float* priors = out + OFF_PRIORS;
  float* posts = out + OFF_POSTS;
  float* xtraj = out + OFF_XTRAJ;
  const long pbase = (long)g * Nn;
  const float* aptr = act + ((long)g * Tt + WL - 1) * 8;

  const float2 s0v = *reinterpret_cast<const float2*>(priors + pbase * 2);
  float x0p = 0.f, x1p = 0.f;
  float s0p = s0v.x, s1p = s0v.y;
  if (lane == 0)
    *reinterpret_cast<float2*>(xtraj + pbase * 2) = make_float2(0.f, 0.f);
  if (lane == 1)
    *reinterpret_cast<float2*>(posts + pbase * 2) = make_float2(s0p, s1p);

  float4 an0 = *reinterpret_cast<const float4*>(aptr);
  float4 an1 = *reinterpret_cast<const float4*>(aptr + 4);
  float2 prn = s0v;
  int mn = mask[pbase];

  for (int t = 0; t < Nn - 1; ++t) {
    const float4 a0 = an0, a1 = an1;
    const float2 pr = prn;
    const int m = mn;
    const int tn1 = (t + 1 < Nn - 1) ? t + 1 : Nn - 2;
    an0 = *reinterpret_cast<const float4*>(aptr + (long)tn1 * 8);
    an1 = *reinterpret_cast<const float4*>(aptr + (long)tn1 * 8 + 4);
    prn = *reinterpret_cast<const float2*>(priors + (pbase + t + 1) * 2);
    mn = mask[pbase + t + 1];

    const float st0 = m ? pr.x : s0p;
    const float st1 = m ? pr.y : s1p;

    float giq[6], ghq[6];
#pragma unroll
    for (int q = 0; q < 6; ++q) {
      float acc = bihv[q];
      acc = fmaf(a0.x, wihA[0][q], acc);
      acc = fmaf(a0.y, wihA[1][q], acc);
      acc = fmaf(a0.z, wihA[2][q], acc);
      acc = fmaf(a0.w, wihA[3][q], acc);
      acc = fmaf(a1.x, wihA[4][q], acc);
      acc = fmaf(a1.y, wihA[5][q], acc);
      acc = fmaf(a1.z, wihA[6][q], acc);
      acc = fmaf(a1.w, wihA[7][q], acc);
      giq[q] = fmaf(st1, wih9[q], fmaf(st0, wih8[q], acc));
      ghq[q] = fmaf(x1p, whh1[q], fmaf(x0p, whh0[q], bhhv[q]));
    }
    const float r0 = sigmoidf_(giq[0] + ghq[0]);
    const float r1 = sigmoidf_(giq[1] + ghq[1]);
    const float z0 = sigmoidf_(giq[2] + ghq[2]);
    const float z1 = sigmoidf_(giq[3] + ghq[3]);
    const float nn0 = tanh_(fmaf(r0, ghq[4], giq[4]));
    const float nn1 = tanh_(fmaf(r1, ghq[5], giq[5]));
    const float xn0 = fmaf(z0, x0p - nn0, nn0);
    const float xn1 = fmaf(z1, x1p - nn1, nn1);

    const float h1 = fmaxf(fmaf(xn1, w1c1, fmaf(xn0, w1c0, b1v)), 0.0f);
    float ha[16];
#pragma unroll
    for (int k = 0; k < 16; ++k) ha[k] = __shfl(h1, k, 16);
    float q0 = fmaf(ha[0], w2c[0], b2v);
    q0 = fmaf(ha[1], w2c[1], q0);
    q0 = fmaf(ha[2], w2c[2], q0);
    q0 = fmaf(ha[3], w2c[3], q0);
    float q1 = ha[4] * w2c[4];
    q1 = fmaf(ha[5], w2c[5], q1);
    q1 = fmaf(ha[6], w2c[6], q1);
    q1 = fmaf(ha[7], w2c[7], q1);
    float q2 = ha[8] * w2c[8];
    q2 = fmaf(ha[9], w2c[9], q2);
    q2 = fmaf(ha[10], w2c[10], q2);
    q2 = fmaf(ha[11], w2c[11], q2);
    float q3 = ha[12] * w2c[12];
    q3 = fmaf(ha[13], w2c[13], q3);
    q3 = fmaf(ha[14], w2c[14], q3);
    q3 = fmaf(ha[15], w2c[15], q3);
    const float h2 = fmaxf((q0 + q1) + (q2 + q3), 0.0f);

    float p0 = row16_allsum(h2 * w3a);
    float p1 = row16_allsum(h2 * w3b);
    const float sn0 = p0 + b3a;
    const float sn1 = p1 + b3b;

    if (lane == 0)
      *reinterpret_cast<float2*>(xtraj + (pbase + t + 1) * 2) =
          make_float2(xn0, xn1);
    if (lane == 1)
      *reinterpret_cast<float2*>(posts + (pbase + t + 1) * 2) =
          make_float2(sn0, sn1);
    x0p = xn0; x1p = xn1; s0p = sn0; s1p = sn1;
  }
}

}  // namespace

extern "C" void kernel_launch(void* const* d_in, const int* in_sizes, int n_in,
                              void* d_out, int out_size, void* d_ws, size_t ws_size,
                              hipStream_t stream) {
  const float* obs    = (const float*)d_in[0];
  const float* action = (const float*)d_in[1];
  const int* t_label  = (const int*)d_in[2];
  const int* mask     = (const int*)d_in[3];
  const float* enc_W1 = (const float*)d_in[4];
  const float* enc_b1 = (const float*)d_in[5];
  const float* enc_W2 = (const float*)d_in[6];
  const float* enc_b2 = (const float*)d_in[7];
  const float* enc_W3 = (const float*)d_in[8];
  const float* enc_b3 = (const float*)d_in[9];
  const float* gru_Wih = (const float*)d_in[10];
  const float* gru_Whh = (const float*)d_in[11];
  const float* gru_bih = (const float*)d_in[12];
  const float* gru_bhh = (const float*)d_in[13];
  const float* post_W1 = (const float*)d_in[14];
  const float* post_b1 = (const float*)d_in[15];
  const float* post_W2 = (const float*)d_in[16];
  const float* post_b2 = (const float*)d_in[17];
  const float* post_W3 = (const float*)d_in[18];
  const float* post_b3 = (const float*)d_in[19];
  const float* dec_W1 = (const float*)d_in[20];
  const float* dec_b1 = (const float*)d_in[21];
  const float* dec_W2 = (const float*)d_in[22];
  const float* dec_b2 = (const float*)d_in[23];
  const float* dec_W3 = (const float*)d_in[24];
  const float* dec_b3 = (const float*)d_in[25];
  float* out = (float*)d_out;

  pack_kernel<<<(PK_TOTAL + 255) / 256, 256, 0, stream>>>(
      enc_W1, enc_W2, enc_W3, dec_W1, dec_W2, dec_W3);

  enc_mfma<<<Bb * 8, 256, 0, stream>>>(obs, action, enc_b1, enc_b2, enc_b3,
                                       out);

  const size_t rec_bytes = (size_t)Bb * REC_T * 12 * sizeof(float);
  if (ws_size >= rec_bytes) {
    float* rec = (float*)d_ws;
    const int total = Bb * REC_T;
    gprep_kernel<<<(total + 255) / 256, 256, 0, stream>>>(
        action, mask, gru_Wih, gru_bih, out, rec);
    scan5_kernel<<<32, 64, 0, stream>>>(rec, post_W2, post_W1, post_b1,
                                        post_b2, post_W3, post_b3, gru_Wih,
                                        gru_Whh, gru_bhh, out);
  } else {
    scan_fb_kernel<<<128, 64, 0, stream>>>(
        action, mask, gru_Wih, gru_Whh, gru_bih, gru_bhh, post_W1, post_b1,
        post_W2, post_b2, post_W3, post_b3, out);
  }

  dec_mfma<<<Bb * 8, 256, 0, stream>>>(action, dec_b1, dec_b2, dec_b3, out);
  copy_kernel<<<2048, 256, 0, stream>>>(obs, t_label, out);
}

// Round 9
// 240.647 us; speedup vs baseline: 2.8974x; 2.8974x over previous
//
#include <hip/hip_runtime.h>
#include <hip/hip_bf16.h>

namespace {

constexpr int Bb = 512;
constexpr int Tt = 512;
constexpr int OD = 32;
constexpr int AD = 8;
constexpr int WL = 10;
constexpr int Nn = Tt - WL + 1;   // 503
constexpr int CH = OD + AD;       // 40
constexpr int REC_T = 512;        // padded step count (32 chunks x 16)

constexpr float LOG2E = 1.4426950408889634f;

constexpr long SZ_PO = (long)Bb * Nn * 32;
constexpr long SZ_PR = (long)Bb * Nn * 2;
constexpr long OFF_POST   = 0;
constexpr long OFF_PRIORS = SZ_PO;
constexpr long OFF_POSTS  = OFF_PRIORS + SZ_PR;
constexpr long OFF_XTRAJ  = OFF_POSTS + SZ_PR;
constexpr long OFF_TGT    = OFF_XTRAJ + SZ_PR;
constexpr long OFF_LAB    = OFF_TGT + SZ_PO;

constexpr int PK_W1  = 0;
constexpr int PK_W2  = 26624;
constexpr int PK_W3  = 30720;
constexpr int PK_DW1 = 31744;
constexpr int PK_DW2 = 33792;
constexpr int PK_DW3 = 37888;
constexpr int PK_TOTAL = 39936;

typedef __attribute__((ext_vector_type(8))) short bf16x8;
typedef __attribute__((ext_vector_type(4))) float f32x4;

__device__ __align__(16) short g_pack[PK_TOTAL];

__device__ __forceinline__ f32x4 mfma16(bf16x8 a, bf16x8 b, f32x4 c) {
  return __builtin_amdgcn_mfma_f32_16x16x32_bf16(a, b, c, 0, 0, 0);
}

__device__ __forceinline__ unsigned short f2bf(float x) {
  unsigned int u = __float_as_uint(x);
  unsigned int r = u + 0x7fffu + ((u >> 16) & 1u);
  return (unsigned short)(r >> 16);
}

__device__ __forceinline__ float sigmoidf_(float x) {
  return 1.0f / (1.0f + __expf(-x));
}
__device__ __forceinline__ float tanh_(float x) {
  return 1.0f - 2.0f / (__expf(2.0f * x) + 1.0f);
}

template <int CTRL>
__device__ __forceinline__ float dpp_add(float x) {
  int y = __builtin_amdgcn_update_dpp(0, __float_as_int(x), CTRL, 0xf, 0xf, false);
  return x + __int_as_float(y);
}
template <int CTRL>
__device__ __forceinline__ float dpp_mov(float x) {
  return __int_as_float(
      __builtin_amdgcn_update_dpp(0, __float_as_int(x), CTRL, 0xf, 0xf, false));
}
__device__ __forceinline__ float row16_allsum(float x) {
  x = dpp_add<0xB1>(x);
  x = dpp_add<0x4E>(x);
  x = dpp_add<0x141>(x);
  x = dpp_add<0x140>(x);
  return x;
}

// ---------------- weight prepack ----------------
__global__ __launch_bounds__(256) void pack_kernel(
    const float* __restrict__ W1, const float* __restrict__ W2,
    const float* __restrict__ W3, const float* __restrict__ dW1,
    const float* __restrict__ dW2, const float* __restrict__ dW3) {
  const int idx = blockIdx.x * 256 + threadIdx.x;
  if (idx >= PK_TOTAL) return;
  float v = 0.0f;
  int base, r;
  if (idx < PK_W2) {
    base = PK_W1; r = idx - base;
    const int frag = r >> 9, inner = r & 511;
    const int lane = inner >> 3, j = inner & 7;
    const int kb = frag >> 2, jb = frag & 3;
    const int col = lane & 15;
    const int kp = kb * 32 + ((lane >> 4) << 3) + j;
    if (kp < 400) {
      const int w = kp / 40, c = kp - w * 40;
      v = W1[(c * 10 + w) * 64 + jb * 16 + col];
    }
  } else if (idx < PK_W3) {
    base = PK_W2; r = idx - base;
    const int frag = r >> 9, inner = r & 511;
    const int lane = inner >> 3, j = inner & 7;
    const int kb = frag >> 2, jb = frag & 3;
    const int col = lane & 15;
    const int k = kb * 32 + ((lane >> 4) << 3) + j;
    v = W2[k * 64 + jb * 16 + col];
  } else if (idx < PK_DW1) {
    base = PK_W3; r = idx - base;
    const int frag = r >> 9, inner = r & 511;
    const int lane = inner >> 3, j = inner & 7;
    const int kb = frag;
    const int col = lane & 15;
    const int k = kb * 32 + ((lane >> 4) << 3) + j;
    v = (col < 2) ? W3[k * 2 + col] : 0.0f;
  } else if (idx < PK_DW2) {
    base = PK_DW1; r = idx - base;
    const int frag = r >> 9, inner = r & 511;
    const int lane = inner >> 3, j = inner & 7;
    const int jb = frag;
    const int col = lane & 15;
    const int k = ((lane >> 4) << 3) + j;
    v = (k < 10) ? dW1[k * 64 + jb * 16 + col] : 0.0f;
  } else if (idx < PK_DW3) {
    base = PK_DW2; r = idx - base;
    const int frag = r >> 9, inner = r & 511;
    const int lane = inner >> 3, j = inner & 7;
    const int kb = frag >> 2, jb = frag & 3;
    const int col = lane & 15;
    const int k = kb * 32 + ((lane >> 4) << 3) + j;
    v = dW2[k * 64 + jb * 16 + col];
  } else {
    base = PK_DW3; r = idx - base;
    const int frag = r >> 9, inner = r & 511;
    const int lane = inner >> 3, j = inner & 7;
    const int kb = frag >> 1, jb = frag & 1;
    const int col = lane & 15;
    const int k = kb * 32 + ((lane >> 4) << 3) + j;
    v = dW3[k * 32 + jb * 16 + col];
  }
  g_pack[idx] = (short)f2bf(v);
}

// ---------------- standalone copy (fallback path only) ----------------
__global__ void copy_kernel(const float* __restrict__ obs,
                            const int* __restrict__ tlab,
                            float* __restrict__ out) {
  const int total4 = (int)(SZ_PO / 4);
  const int totalL = Bb * Nn;
  const int stride = gridDim.x * blockDim.x;
  float4* out4 = reinterpret_cast<float4*>(out + OFF_TGT);
  const float4* obs4 = reinterpret_cast<const float4*>(obs);
  for (int idx = blockIdx.x * blockDim.x + threadIdx.x;
       idx < total4 + totalL; idx += stride) {
    if (idx < total4) {
      const int b = idx / (Nn * 8);
      const int r = idx - b * (Nn * 8);
      const int n = r >> 3;
      const int c4 = r & 7;
      out4[idx] = obs4[((long)b * Tt + n + WL - 1) * 8 + c4];
    } else {
      const int j = idx - total4;
      const int b = j / Nn;
      const int n = j - b * Nn;
      out[OFF_LAB + j] = (float)tlab[(long)b * Tt + n + WL - 1];
    }
  }
}

// ---------------- encoder (MFMA) ----------------
__global__ __launch_bounds__(256) void enc_mfma(
    const float* __restrict__ obs, const float* __restrict__ act,
    const float* __restrict__ b1, const float* __restrict__ b2,
    const float* __restrict__ b3, float* __restrict__ out) {
  __shared__ __align__(16) unsigned short sA[74 * 40];
  __shared__ __align__(16) unsigned short sH1[64 * 64];
  __shared__ __align__(16) unsigned short sH2[64 * 64];
  const int b = blockIdx.x >> 3;
  const int n0 = (blockIdx.x & 7) << 6;
  const int tid = threadIdx.x;
  const int lane = tid & 63, wv = tid >> 6;
  const int q = lane >> 4, lr = lane & 15;
  const int nl = wv * 16 + lr;

  for (int e = tid; e < 74 * 40; e += 256) {
    const int row = e / 40, c = e - row * 40;
    int t = n0 + row; t = t < Tt ? t : Tt - 1;
    const float v = (c < OD) ? obs[((long)b * Tt + t) * OD + c]
                             : act[((long)b * Tt + t) * AD + c - OD];
    sA[e] = f2bf(v);
  }
  __syncthreads();

  const char* sAb = (const char*)sA;
  f32x4 acc[4] = {{0,0,0,0},{0,0,0,0},{0,0,0,0},{0,0,0,0}};
  {
    int c0 = q * 8, w = 0;
#pragma unroll
    for (int kb = 0; kb < 13; ++kb) {
      const bf16x8 a = *(const bf16x8*)(sAb + (nl + w) * 80 + c0 * 2);
#pragma unroll
      for (int jb = 0; jb < 4; ++jb) {
        const bf16x8 bw =
            *(const bf16x8*)&g_pack[PK_W1 + ((kb * 4 + jb) * 64 + lane) * 8];
        acc[jb] = mfma16(a, bw, acc[jb]);
      }
      c0 += 32;
      if (c0 >= 40) { c0 -= 40; ++w; }
    }
  }
  {
#pragma unroll
    for (int jb = 0; jb < 4; ++jb) {
      const float bb = b1[jb * 16 + lr];
#pragma unroll
      for (int r = 0; r < 4; ++r) {
        const int grow = wv * 16 + q * 4 + r;
        const int col = jb * 16 + lr;
        const float v = fmaxf(acc[jb][r] + bb, 0.0f);
        const int byte = (grow * 128 + col * 2) ^ ((grow & 7) << 4);
        *(unsigned short*)((char*)sH1 + byte) = f2bf(v);
      }
    }
  }
  __syncthreads();

  f32x4 ac2[4] = {{0,0,0,0},{0,0,0,0},{0,0,0,0},{0,0,0,0}};
#pragma unroll
  for (int kb = 0; kb < 2; ++kb) {
    const int byte = (nl * 128 + kb * 64 + q * 16) ^ ((lr & 7) << 4);
    const bf16x8 a = *(const bf16x8*)((const char*)sH1 + byte);
#pragma unroll
    for (int jb = 0; jb < 4; ++jb) {
      const bf16x8 bw =
          *(const bf16x8*)&g_pack[PK_W2 + ((kb * 4 + jb) * 64 + lane) * 8];
      ac2[jb] = mfma16(a, bw, ac2[jb]);
    }
  }
  {
#pragma unroll
    for (int jb = 0; jb < 4; ++jb) {
      const float bb = b2[jb * 16 + lr];
#pragma unroll
      for (int r = 0; r < 4; ++r) {
        const int grow = wv * 16 + q * 4 + r;
        const int col = jb * 16 + lr;
        const float v = fmaxf(ac2[jb][r] + bb, 0.0f);
        const int byte = (grow * 128 + col * 2) ^ ((grow & 7) << 4);
        *(unsigned short*)((char*)sH2 + byte) = f2bf(v);
      }
    }
  }
  __syncthreads();

  f32x4 ac3 = {0, 0, 0, 0};
#pragma unroll
  for (int kb = 0; kb < 2; ++kb) {
    const int byte = (nl * 128 + kb * 64 + q * 16) ^ ((lr & 7) << 4);
    const bf16x8 a = *(const bf16x8*)((const char*)sH2 + byte);
    const bf16x8 bw = *(const bf16x8*)&g_pack[PK_W3 + (kb * 64 + lane) * 8];
    ac3 = mfma16(a, bw, ac3);
  }
  if (lr < 2) {
    const float bb = b3[lr];
#pragma unroll
    for (int r = 0; r < 4; ++r) {
      const int grow = wv * 16 + q * 4 + r;
      const int n = n0 + grow;
      if (n < Nn) out[OFF_PRIORS + ((long)b * Nn + n) * 2 + lr] = ac3[r] + bb;
    }
  }
}

// ---------------- decoder (MFMA) ----------------
__global__ __launch_bounds__(256) void dec_mfma(
    const float* __restrict__ act, const float* __restrict__ b1,
    const float* __restrict__ b2, const float* __restrict__ b3,
    float* __restrict__ out) {
  __shared__ __align__(16) unsigned short sD[64 * 32];
  __shared__ __align__(16) unsigned short sH1[64 * 64];
  __shared__ __align__(16) unsigned short sH2[64 * 64];
  const int b = blockIdx.x >> 3;
  const int n0 = (blockIdx.x & 7) << 6;
  const int tid = threadIdx.x;
  const int lane = tid & 63, wv = tid >> 6;
  const int q = lane >> 4, lr = lane & 15;
  const int nl = wv * 16 + lr;
  const float* posts = out + OFF_POSTS;

  for (int e = tid; e < 64 * 32; e += 256) {
    const int row = e >> 5, c = e & 31;
    int n = n0 + row; n = n < Nn ? n : Nn - 1;
    float v = 0.0f;
    if (c < 2) v = posts[((long)b * Nn + n) * 2 + c];
    else if (c < 10) v = act[((long)b * Tt + n + WL - 1) * AD + c - 2];
    const int byte = (row * 64 + c * 2) ^ ((row & 3) << 4);
    *(unsigned short*)((char*)sD + byte) = f2bf(v);
  }
  __syncthreads();

  f32x4 acc[4] = {{0,0,0,0},{0,0,0,0},{0,0,0,0},{0,0,0,0}};
  {
    const int byte = (nl * 64 + q * 16) ^ ((nl & 3) << 4);
    const bf16x8 a = *(const bf16x8*)((const char*)sD + byte);
#pragma unroll
    for (int jb = 0; jb < 4; ++jb) {
      const bf16x8 bw = *(const bf16x8*)&g_pack[PK_DW1 + (jb * 64 + lane) * 8];
      acc[jb] = mfma16(a, bw, acc[jb]);
    }
  }
  {
#pragma unroll
    for (int jb = 0; jb < 4; ++jb) {
      const float bb = b1[jb * 16 + lr];
#pragma unroll
      for (int r = 0; r < 4; ++r) {
        const int grow = wv * 16 + q * 4 + r;
        const int col = jb * 16 + lr;
        const float v = fmaxf(acc[jb][r] + bb, 0.0f);
        const int byte = (grow * 128 + col * 2) ^ ((grow & 7) << 4);
        *(unsigned short*)((char*)sH1 + byte) = f2bf(v);
      }
    }
  }
  __syncthreads();

  f32x4 ac2[4] = {{0,0,0,0},{0,0,0,0},{0,0,0,0},{0,0,0,0}};
#pragma unroll
  for (int kb = 0; kb < 2; ++kb) {
    const int byte = (nl * 128 + kb * 64 + q * 16) ^ ((lr & 7) << 4);
    const bf16x8 a = *(const bf16x8*)((const char*)sH1 + byte);
#pragma unroll
    for (int jb = 0; jb < 4; ++jb) {
      const bf16x8 bw =
          *(const bf16x8*)&g_pack[PK_DW2 + ((kb * 4 + jb) * 64 + lane) * 8];
      ac2[jb] = mfma16(a, bw, ac2[jb]);
    }
  }
  {
#pragma unroll
    for (int jb = 0; jb < 4; ++jb) {
      const float bb = b2[jb * 16 + lr];
#pragma unroll
      for (int r = 0; r < 4; ++r) {
        const int grow = wv * 16 + q * 4 + r;
        const int col = jb * 16 + lr;
        const float v = fmaxf(ac2[jb][r] + bb, 0.0f);
        const int byte = (grow * 128 + col * 2) ^ ((grow & 7) << 4);
        *(unsigned short*)((char*)sH2 + byte) = f2bf(v);
      }
    }
  }
  __syncthreads();

  f32x4 ac3[2] = {{0,0,0,0},{0,0,0,0}};
#pragma unroll
  for (int kb = 0; kb < 2; ++kb) {
    const int byte = (nl * 128 + kb * 64 + q * 16) ^ ((lr & 7) << 4);
    const bf16x8 a = *(const bf16x8*)((const char*)sH2 + byte);
#pragma unroll
    for (int jb = 0; jb < 2; ++jb) {
      const bf16x8 bw =
          *(const bf16x8*)&g_pack[PK_DW3 + ((kb * 2 + jb) * 64 + lane) * 8];
      ac3[jb] = mfma16(a, bw, ac3[jb]);
    }
  }
#pragma unroll
  for (int jb = 0; jb < 2; ++jb) {
    const int o = jb * 16 + lr;
    const float bb = b3[o];
#pragma unroll
    for (int r = 0; r < 4; ++r) {
      const int grow = wv * 16 + q * 4 + r;
      const int n = n0 + grow;
      if (n < Nn) out[OFF_POST + ((long)b * Nn + n) * 32 + o] = ac3[jb][r] + bb;
    }
  }
}

// ---------------- gprep: per-step scan records ----------------
// rec[blk(128)][t][sub(4)][12] = {gia0..5 (gate-scaled), pr0, pr1, mfloat, pad}
__global__ __launch_bounds__(256) void gprep_kernel(
    const float* __restrict__ act, const int* __restrict__ mask,
    const float* __restrict__ Wih, const float* __restrict__ bih,
    const float* __restrict__ out, float* __restrict__ rec) {
  const int idx = blockIdx.x * 256 + threadIdx.x;
  const int total = Bb * REC_T;
  if (idx >= total) return;
  const int sub = idx & 3;
  const int t = (idx >> 2) & (REC_T - 1);
  const int blk = idx >> 11;
  const int g = (blk << 2) + sub;
  const float sc[6] = {-LOG2E, -LOG2E, -LOG2E, -LOG2E, 2.f * LOG2E, 2.f * LOG2E};
  float r[12];
#pragma unroll
  for (int i = 0; i < 12; ++i) r[i] = 0.0f;
  if (t < Nn - 1) {
    const float* a = act + ((long)g * Tt + WL - 1 + t) * AD;
    const float4 a0 = *reinterpret_cast<const float4*>(a);
    const float4 a1 = *reinterpret_cast<const float4*>(a + 4);
#pragma unroll
    for (int q = 0; q < 6; ++q) {
      float acc = bih[q];
      acc = fmaf(a0.x, Wih[0 * 6 + q], acc);
      acc = fmaf(a0.y, Wih[1 * 6 + q], acc);
      acc = fmaf(a0.z, Wih[2 * 6 + q], acc);
      acc = fmaf(a0.w, Wih[3 * 6 + q], acc);
      acc = fmaf(a1.x, Wih[4 * 6 + q], acc);
      acc = fmaf(a1.y, Wih[5 * 6 + q], acc);
      acc = fmaf(a1.z, Wih[6 * 6 + q], acc);
      acc = fmaf(a1.w, Wih[7 * 6 + q], acc);
      r[q] = acc * sc[q];
    }
    const float2 pr =
        *reinterpret_cast<const float2*>(out + OFF_PRIORS + ((long)g * Nn + t) * 2);
    r[6] = pr.x;
    r[7] = pr.y;
    r[8] = (float)mask[(long)g * Nn + t];
  }
  float4* o = reinterpret_cast<float4*>(rec + (long)idx * 12);
  o[0] = make_float4(r[0], r[1], r[2], r[3]);
  o[1] = make_float4(r[4], r[5], r[6], r[7]);
  o[2] = make_float4(r[8], r[9], r[10], r[11]);
}

// ---------------- scan (round-7 structure) + fused copy on extra blocks ----------------
#define SCAN_STEP(GA, GB, MF, TG)                                           \
  do {                                                                      \
    const bool mm = ((MF) != 0.0f);                                         \
    const float st0 = mm ? (GB).z : s0p;                                    \
    const float st1 = mm ? (GB).w : s1p;                                    \
    float giq[6], ghq[6];                                                   \
    _Pragma("unroll") for (int q_ = 0; q_ < 6; ++q_) ghq[q_] =              \
        fmaf(x1p, whh1[q_], fmaf(x0p, whh0[q_], bhhv[q_]));                 \
    giq[0] = fmaf(st1, wih9[0], fmaf(st0, wih8[0], (GA).x));                \
    giq[1] = fmaf(st1, wih9[1], fmaf(st0, wih8[1], (GA).y));                \
    giq[2] = fmaf(st1, wih9[2], fmaf(st0, wih8[2], (GA).z));                \
    giq[3] = fmaf(st1, wih9[3], fmaf(st0, wih8[3], (GA).w));                \
    giq[4] = fmaf(st1, wih9[4], fmaf(st0, wih8[4], (GB).x));                \
    giq[5] = fmaf(st1, wih9[5], fmaf(st0, wih8[5], (GB).y));                \
    const float e0 = __builtin_amdgcn_exp2f(giq[0] + ghq[0]);               \
    const float e1 = __builtin_amdgcn_exp2f(giq[1] + ghq[1]);               \
    const float e2 = __builtin_amdgcn_exp2f(giq[2] + ghq[2]);               \
    const float e3 = __builtin_amdgcn_exp2f(giq[3] + ghq[3]);               \
    const float r0 = __builtin_amdgcn_rcpf(1.0f + e0);                      \
    const float r1 = __builtin_amdgcn_rcpf(1.0f + e1);                      \
    const float z0 = __builtin_amdgcn_rcpf(1.0f + e2);                      \
    const float z1 = __builtin_amdgcn_rcpf(1.0f + e3);                      \
    const float en0 = __builtin_amdgcn_exp2f(fmaf(r0, ghq[4], giq[4]));     \
    const float en1 = __builtin_amdgcn_exp2f(fmaf(r1, ghq[5], giq[5]));     \
    const float nn0 = fmaf(-2.0f, __builtin_amdgcn_rcpf(1.0f + en0), 1.0f); \
    const float nn1 = fmaf(-2.0f, __builtin_amdgcn_rcpf(1.0f + en1), 1.0f); \
    const float xn0 = fmaf(z0, x0p - nn0, nn0);                             \
    const float xn1 = fmaf(z1, x1p - nn1, nn1);                             \
    const float h1 = fmaxf(fmaf(xn1, w1c1, fmaf(xn0, w1c0, b1v)), 0.0f);    \
    const float t0 = h1;                                                    \
    const float t1 = dpp_mov<0xB1>(t0);                                     \
    const float t2 = dpp_mov<0x4E>(t0);                                     \
    const float t3 = dpp_mov<0x4E>(t1);                                     \
    const float t4 = dpp_mov<0x141>(t0);                                    \
    const float t5 = dpp_mov<0x141>(t1);                                    \
    const float t6 = dpp_mov<0x141>(t2);                                    \
    const float t7 = dpp_mov<0x141>(t3);                                    \
    const float t8 = dpp_mov<0x128>(t0);                                    \
    const float t9 = dpp_mov<0x128>(t1);                                    \
    const float t10 = dpp_mov<0x128>(t2);                                   \
    const float t11 = dpp_mov<0x128>(t3);                                   \
    const float t12 = dpp_mov<0x128>(t4);                                   \
    const float t13 = dpp_mov<0x128>(t5);                                   \
    const float t14 = dpp_mov<0x128>(t6);                                   \
    const float t15 = dpp_mov<0x128>(t7);                                   \
    float q0 = fmaf(t0, wg[0], b2v);                                        \
    q0 = fmaf(t1, wg[1], q0);                                               \
    q0 = fmaf(t2, wg[2], q0);                                               \
    q0 = fmaf(t3, wg[3], q0);                                               \
    float q1 = t4 * wg[4];                                                  \
    q1 = fmaf(t5, wg[5], q1);                                               \
    q1 = fmaf(t6, wg[6], q1);                                               \
    q1 = fmaf(t7, wg[7], q1);                                               \
    float q2 = t8 * wg[8];                                                  \
    q2 = fmaf(t9, wg[9], q2);                                               \
    q2 = fmaf(t10, wg[10], q2);                                             \
    q2 = fmaf(t11, wg[11], q2);                                             \
    float q3 = t12 * wg[12];                                                \
    q3 = fmaf(t13, wg[13], q3);                                             \
    q3 = fmaf(t14, wg[14], q3);                                             \
    q3 = fmaf(t15, wg[15], q3);                                             \
    const float h2 = fmaxf((q0 + q1) + (q2 + q3), 0.0f);                    \
    float p0 = row16_allsum(h2 * w3a);                                      \
    float p1 = row16_allsum(h2 * w3b);                                      \
    const float sn0 = p0 + b3a;                                             \
    const float sn1 = p1 + b3b;                                             \
    if (lane == 0 && (TG) < Nn - 1)                                         \
      *reinterpret_cast<float2*>(xw) = make_float2(xn0, xn1);               \
    if (lane == 1 && (TG) < Nn - 1)                                         \
      *reinterpret_cast<float2*>(sw) = make_float2(sn0, sn1);               \
    xw += 2;                                                                \
    sw += 2;                                                                \
    x0p = xn0;                                                              \
    x1p = xn1;                                                              \
    s0p = sn0;                                                              \
    s1p = sn1;                                                              \
  } while (0)

#define LOADCH(C)                                                     \
  do {                                                                \
    const float* p_ = gsrc + (C) * 768 + tid * 12;                    \
    st0 = *reinterpret_cast<const float4*>(p_);                       \
    st1 = *reinterpret_cast<const float4*>(p_ + 4);                   \
    st2 = *reinterpret_cast<const float4*>(p_ + 8);                   \
  } while (0)
#define WRITECH(BUF)                                                  \
  do {                                                                \
    float* q_ = &slds[BUF][tid * 12];                                 \
    *reinterpret_cast<float4*>(q_) = st0;                             \
    *reinterpret_cast<float4*>(q_ + 4) = st1;                         \
    *reinterpret_cast<float4*>(q_ + 8) = st2;                         \
  } while (0)

__global__ __launch_bounds__(64, 1) void scan4_kernel(
    const float* __restrict__ rec, const float* __restrict__ pW2,
    const float* __restrict__ pW1, const float* __restrict__ pb1,
    const float* __restrict__ pb2, const float* __restrict__ pW3,
    const float* __restrict__ pb3, const float* __restrict__ Wih,
    const float* __restrict__ Whh, const float* __restrict__ bhh,
    const float* __restrict__ obs, const int* __restrict__ tlab,
    float* __restrict__ out) {
  __shared__ __align__(16) float slds[2][768];
  const int tid = threadIdx.x;

  // blocks >= 128: fused copy (runs on CUs the scan leaves idle)
  if (blockIdx.x >= 128) {
    const int total4 = (int)(SZ_PO / 4);
    const int totalL = Bb * Nn;
    const int stride = (gridDim.x - 128) * 64;
    float4* out4 = reinterpret_cast<float4*>(out + OFF_TGT);
    const float4* obs4 = reinterpret_cast<const float4*>(obs);
    for (int idx = (blockIdx.x - 128) * 64 + tid; idx < total4 + totalL;
         idx += stride) {
      if (idx < total4) {
        const int b = idx / (Nn * 8);
        const int r = idx - b * (Nn * 8);
        const int n = r >> 3;
        const int c4 = r & 7;
        out4[idx] = obs4[((long)b * Tt + n + WL - 1) * 8 + c4];
      } else {
        const int j = idx - total4;
        const int b = j / Nn;
        const int n = j - b * Nn;
        out[OFF_LAB + j] = (float)tlab[(long)b * Tt + n + WL - 1];
      }
    }
    return;
  }

  const int lane = tid & 15;
  const int sub = tid >> 4;
  const int blk = blockIdx.x;
  const int g = (blk << 2) + sub;

  const float sc[6] = {-LOG2E, -LOG2E, -LOG2E, -LOG2E, 2.f * LOG2E, 2.f * LOG2E};
  float wih8[6], wih9[6], whh0[6], whh1[6], bhhv[6];
#pragma unroll
  for (int q = 0; q < 6; ++q) {
    wih8[q] = Wih[8 * 6 + q] * sc[q];
    wih9[q] = Wih[9 * 6 + q] * sc[q];
    whh0[q] = Whh[q] * sc[q];
    whh1[q] = Whh[6 + q] * sc[q];
    bhhv[q] = bhh[q] * sc[q];
  }
  const float w1c0 = pW1[lane], w1c1 = pW1[16 + lane], b1v = pb1[lane];
  constexpr int otab[16] = {0, 1, 2, 3, 7, 6, 5, 4, 8, 9, 10, 11, 15, 14, 13, 12};
  float wg[16];
#pragma unroll
  for (int i = 0; i < 16; ++i) wg[i] = pW2[(lane ^ otab[i]) * 16 + lane];
  const float b2v = pb2[lane];
  const float w3a = pW3[lane * 2], w3b = pW3[lane * 2 + 1];
  const float b3a = pb3[0], b3b = pb3[1];

  const float* priors = out + OFF_PRIORS;
  const long pbase = (long)g * Nn;
  const float* gsrc = rec + (long)blk * (REC_T * 48);
  float* xw = out + OFF_XTRAJ + pbase * 2 + 2;
  float* sw = out + OFF_POSTS + pbase * 2 + 2;

  const float2 s0v = *reinterpret_cast<const float2*>(priors + pbase * 2);
  float x0p = 0.f, x1p = 0.f;
  float s0p = s0v.x, s1p = s0v.y;
  if (lane == 0)
    *reinterpret_cast<float2*>(out + OFF_XTRAJ + pbase * 2) =
        make_float2(0.f, 0.f);
  if (lane == 1)
    *reinterpret_cast<float2*>(out + OFF_POSTS + pbase * 2) =
        make_float2(s0p, s1p);

  float4 st0, st1, st2;
  LOADCH(0);
  WRITECH(0);
  LOADCH(1);   // chunk 1 in flight during chunk 0's compute

  // prefetch step (0,0)
  float4 cGA, cGB;
  float cMF;
  {
    const float* rp = &slds[0][(sub)*12];
    cGA = *reinterpret_cast<const float4*>(rp);
    cGB = *reinterpret_cast<const float4*>(rp + 4);
    cMF = rp[8];
  }

  int tg = 0;
  for (int c = 0; c < 32; ++c) {
    const int buf = c & 1;
    if (c + 1 < 32) WRITECH((c + 1) & 1);
    if (c + 2 < 32) LOADCH(c + 2);
#pragma unroll
    for (int tl = 0; tl < 16; ++tl) {
      const float4 GA = cGA;
      const float4 GB = cGB;
      const float MF = cMF;
      const int ntl = (tl + 1) & 15;
      const int nbuf = (tl == 15) ? (buf ^ 1) : buf;
      const float* rp = &slds[nbuf][(ntl * 4 + sub) * 12];
      cGA = *reinterpret_cast<const float4*>(rp);
      cGB = *reinterpret_cast<const float4*>(rp + 4);
      cMF = rp[8];
      SCAN_STEP(GA, GB, MF, tg);
      ++tg;
    }
  }
}

// ---------------- fallback scan (no workspace) ----------------
__global__ __launch_bounds__(64) void scan_fb_kernel(
    const float* __restrict__ act, const int* __restrict__ mask,
    const float* __restrict__ Wih, const float* __restrict__ Whh,
    const float* __restrict__ bih, const float* __restrict__ bhh,
    const float* __restrict__ pW1, const float* __restrict__ pb1,
    const float* __restrict__ pW2, const float* __restrict__ pb2,
    const float* __restrict__ pW3, const float* __restrict__ pb3,
    float* __restrict__ out) {
  const int tid = threadIdx.x;
  const int lane = tid & 15;
  const int g = (blockIdx.x * 64 + tid) >> 4;

  float wih8[6], wih9[6], whh0[6], whh1[6], bhhv[6], bihv[6];
  float wihA[8][6];
#pragma unroll
  for (int q = 0; q < 6; ++q) {
    wih8[q] = Wih[8 * 6 + q];
    wih9[q] = Wih[9 * 6 + q];
    whh0[q] = Whh[q];
    whh1[q] = Whh[6 + q];
    bhhv[q] = bhh[q];
    bihv[q] = bih[q];
  }
#pragma unroll
  for (int i = 0; i < 8; ++i)
#pragma unroll
    for (int q = 0; q < 6; ++q) wihA[i][q] = Wih[i * 6 + q];

  const float w1c0 = pW1[lane], w1c1 = pW1[16 + lane], b1v = pb1[lane];
  float w2c[16];
#pragma unroll
  for (int k = 0; k < 16; ++k) w2c[k] = pW2[k * 16 + lane];
  const float b2v = pb2[lane];
  const float w3a = pW3[lane * 2], w3b = pW3[lane * 2 + 1];
  const float b3a = pb3[0], b3b = pb3[1];

  const float* priors = out + OFF_PRIORS;
  float* posts = out + OFF_POSTS;
  float* xtraj = out + OFF_XTRAJ;
  const long pbase = (long)g * Nn;
  const float* aptr = act + ((long)g * Tt + WL - 1) * 8;

  const float2 s0v = *reinterpret_cast<const float2*>(priors + pbase * 2);
  float x0p = 0.f, x1p = 0.f;
  float s0p = s0v.x, s1p = s0v.y;
  if (lane == 0)
    *reinterpret_cast<float2*>(xtraj + pbase * 2) = make_float2(0.f, 0.f);
  if (lane == 1)
    *reinterpret_cast<float2*>(posts + pbase * 2) = make_float2(s0p, s1p);

  float4 an0 = *reinterpret_cast<const float4*>(aptr);
  float4 an1 = *reinterpret_cast<const float4*>(aptr + 4);
  float2 prn = s0v;
  int mn = mask[pbase];

  for (int t = 0; t < Nn - 1; ++t) {
    const float4 a0 = an0, a1 = an1;
    const float2 pr = prn;
    const int m = mn;
    const int tn1 = (t + 1 < Nn - 1) ? t + 1 : Nn - 2;
    an0 = *reinterpret_cast<const float4*>(aptr + (long)tn1 * 8);
    an1 = *reinterpret_cast<const float4*>(aptr + (long)tn1 * 8 + 4);
    prn = *reinterpret_cast<const float2*>(priors + (pbase + t + 1) * 2);
    mn = mask[pbase + t + 1];

    const float st0 = m ? pr.x : s0p;
    const float st1 = m ? pr.y : s1p;

    float giq[6], ghq[6];
#pragma unroll
    for (int q = 0; q < 6; ++q) {
      float acc = bihv[q];
      acc = fmaf(a0.x, wihA[0][q], acc);
      acc = fmaf(a0.y, wihA[1][q], acc);
      acc = fmaf(a0.z, wihA[2][q], acc);
      acc = fmaf(a0.w, wihA[3][q], acc);
      acc = fmaf(a1.x, wihA[4][q], acc);
      acc = fmaf(a1.y, wihA[5][q], acc);
      acc = fmaf(a1.z, wihA[6][q], acc);
      acc = fmaf(a1.w, wihA[7][q], acc);
      giq[q] = fmaf(st1, wih9[q], fmaf(st0, wih8[q], acc));
      ghq[q] = fmaf(x1p, whh1[q], fmaf(x0p, whh0[q], bhhv[q]));
    }
    const float r0 = sigmoidf_(giq[0] + ghq[0]);
    const float r1 = sigmoidf_(giq[1] + ghq[1]);
    const float z0 = sigmoidf_(giq[2] + ghq[2]);
    const float z1 = sigmoidf_(giq[3] + ghq[3]);
    const float nn0 = tanh_(fmaf(r0, ghq[4], giq[4]));
    const float nn1 = tanh_(fmaf(r1, ghq[5], giq[5]));
    const float xn0 = fmaf(z0, x0p - nn0, nn0);
    const float xn1 = fmaf(z1, x1p - nn1, nn1);

    const float h1 = fmaxf(fmaf(xn1, w1c1, fmaf(xn0, w1c0, b1v)), 0.0f);
    float ha[16];
#pragma unroll
    for (int k = 0; k < 16; ++k) ha[k] = __shfl(h1, k, 16);
    float q0 = fmaf(ha[0], w2c[0], b2v);
    q0 = fmaf(ha[1], w2c[1], q0);
    q0 = fmaf(ha[2], w2c[2], q0);
    q0 = fmaf(ha[3], w2c[3], q0);
    float q1 = ha[4] * w2c[4];
    q1 = fmaf(ha[5], w2c[5], q1);
    q1 = fmaf(ha[6], w2c[6], q1);
    q1 = fmaf(ha[7], w2c[7], q1);
    float q2 = ha[8] * w2c[8];
    q2 = fmaf(ha[9], w2c[9], q2);
    q2 = fmaf(ha[10], w2c[10], q2);
    q2 = fmaf(ha[11], w2c[11], q2);
    float q3 = ha[12] * w2c[12];
    q3 = fmaf(ha[13], w2c[13], q3);
    q3 = fmaf(ha[14], w2c[14], q3);
    q3 = fmaf(ha[15], w2c[15], q3);
    const float h2 = fmaxf((q0 + q1) + (q2 + q3), 0.0f);

    float p0 = row16_allsum(h2 * w3a);
    float p1 = row16_allsum(h2 * w3b);
    const float sn0 = p0 + b3a;
    const float sn1 = p1 + b3b;

    if (lane == 0)
      *reinterpret_cast<float2*>(xtraj + (pbase + t + 1) * 2) =
          make_float2(xn0, xn1);
    if (lane == 1)
      *reinterpret_cast<float2*>(posts + (pbase + t + 1) * 2) =
          make_float2(sn0, sn1);
    x0p = xn0; x1p = xn1; s0p = sn0; s1p = sn1;
  }
}

}  // namespace

extern "C" void kernel_launch(void* const* d_in, const int* in_sizes, int n_in,
                              void* d_out, int out_size, void* d_ws, size_t ws_size,
                              hipStream_t stream) {
  const float* obs    = (const float*)d_in[0];
  const float* action = (const float*)d_in[1];
  const int* t_label  = (const int*)d_in[2];
  const int* mask     = (const int*)d_in[3];
  const float* enc_W1 = (const float*)d_in[4];
  const float* enc_b1 = (const float*)d_in[5];
  const float* enc_W2 = (const float*)d_in[6];
  const float* enc_b2 = (const float*)d_in[7];
  const float* enc_W3 = (const float*)d_in[8];
  const float* enc_b3 = (const float*)d_in[9];
  const float* gru_Wih = (const float*)d_in[10];
  const float* gru_Whh = (const float*)d_in[11];
  const float* gru_bih = (const float*)d_in[12];
  const float* gru_bhh = (const float*)d_in[13];
  const float* post_W1 = (const float*)d_in[14];
  const float* post_b1 = (const float*)d_in[15];
  const float* post_W2 = (const float*)d_in[16];
  const float* post_b2 = (const float*)d_in[17];
  const float* post_W3 = (const float*)d_in[18];
  const float* post_b3 = (const float*)d_in[19];
  const float* dec_W1 = (const float*)d_in[20];
  const float* dec_b1 = (const float*)d_in[21];
  const float* dec_W2 = (const float*)d_in[22];
  const float* dec_b2 = (const float*)d_in[23];
  const float* dec_W3 = (const float*)d_in[24];
  const float* dec_b3 = (const float*)d_in[25];
  float* out = (float*)d_out;

  pack_kernel<<<(PK_TOTAL + 255) / 256, 256, 0, stream>>>(
      enc_W1, enc_W2, enc_W3, dec_W1, dec_W2, dec_W3);

  enc_mfma<<<Bb * 8, 256, 0, stream>>>(obs, action, enc_b1, enc_b2, enc_b3,
                                       out);

  const size_t rec_bytes = (size_t)Bb * REC_T * 12 * sizeof(float);
  if (ws_size >= rec_bytes) {
    float* rec = (float*)d_ws;
    const int total = Bb * REC_T;
    gprep_kernel<<<(total + 255) / 256, 256, 0, stream>>>(
        action, mask, gru_Wih, gru_bih, out, rec);
    // scan blocks [0,128) + fused copy blocks [128, 2176)
    scan4_kernel<<<128 + 2048, 64, 0, stream>>>(
        rec, post_W2, post_W1, post_b1, post_b2, post_W3, post_b3, gru_Wih,
        gru_Whh, gru_bhh, obs, t_label, out);
  } else {
    scan_fb_kernel<<<128, 64, 0, stream>>>(
        action, mask, gru_Wih, gru_Whh, gru_bih, gru_bhh, post_W1, post_b1,
        post_W2, post_b2, post_W3, post_b3, out);
    copy_kernel<<<2048, 256, 0, stream>>>(obs, t_label, out);
  }

  dec_mfma<<<Bb * 8, 256, 0, stream>>>(action, dec_b1, dec_b2, dec_b3, out);
}